// Round 1
// 583.297 us; speedup vs baseline: 1.0765x; 1.0765x over previous
//
#include <hip/hip_runtime.h>
#include <hip/hip_bf16.h>
#include <math.h>

#define D 192
#define RPB 16                       // rows per block -> M = 32 tokens
typedef unsigned short u16;
typedef __attribute__((ext_vector_type(8))) short short8;   // 8 bf16 (4 VGPRs)
typedef __attribute__((ext_vector_type(4))) float float4v;  // MFMA C/D

__device__ __forceinline__ float b2f(u16 u){ union{unsigned i; float f;}c; c.i=(unsigned)u<<16; return c.f; }
__device__ __forceinline__ u16  f2b(float f){
    union{float f; unsigned i;}c; c.f=f;
    unsigned r = c.i + 0x7FFFu + ((c.i>>16)&1u);   // RTNE
    return (u16)(r>>16);
}

// ---- bf16 weight arena in d_ws (row-major [N][K], element offsets) ----
#define WP_OFF   0
#define WT_OFF   36864
#define INW_OFF  73728
#define OUTW_OFF 184320
#define FW1_OFF  221184
#define FW2_OFF  294912
#define CW1_OFF  368640
#define FPW_OFF  405504
#define W_TOTAL  430080            // elements; 860160 bytes

__global__ __launch_bounds__(256)
void cvt_weights(const float* __restrict__ Wp, const float* __restrict__ Wt,
                 const float* __restrict__ in_w, const float* __restrict__ out_w,
                 const float* __restrict__ fw1, const float* __restrict__ fw2,
                 const float* __restrict__ cw1, const float* __restrict__ fpw,
                 u16* __restrict__ ws)
{
    int idx = blockIdx.x * 256 + threadIdx.x;
    if (idx >= W_TOTAL) return;
    const float* src; int off;
    if      (idx < WT_OFF)   { src = Wp;   off = WP_OFF; }
    else if (idx < INW_OFF)  { src = Wt;   off = WT_OFF; }
    else if (idx < OUTW_OFF) { src = in_w; off = INW_OFF; }
    else if (idx < FW1_OFF)  { src = out_w;off = OUTW_OFF; }
    else if (idx < FW2_OFF)  { src = fw1;  off = FW1_OFF; }
    else if (idx < CW1_OFF)  { src = fw2;  off = FW2_OFF; }
    else if (idx < FPW_OFF)  { src = cw1;  off = CW1_OFF; }
    else                     { src = fpw;  off = FPW_OFF; }
    ws[idx] = f2b(src[idx - off]);
}

// A-frag: lane holds A[m = mt*16 + lane16][k = quad*8 + j] for k-step ks (k += 32*ks)
template<int KT, int MT>
__device__ __forceinline__ void load_afrags(short8 (&A)[MT][KT], const u16* base,
                                            int stride, int lane16, int quad)
{
    #pragma unroll
    for (int mt = 0; mt < MT; ++mt)
        #pragma unroll
        for (int ks = 0; ks < KT; ++ks)
            A[mt][ks] = *(const short8*)(base + (mt*16 + lane16)*stride + ks*32 + quad*8);
}

// C tile (M=MT*16, N=NTW*4 waves*16): B streamed from global bf16 [N][K] rows.
// C/D layout: row = quad*4 + reg, col = lane16 (m89-verified).
template<int KT, int MT, int NTW>
__device__ __forceinline__ void run_gemm(const short8 (&A)[MT][KT],
    const u16* __restrict__ wsb, const float* __restrict__ bias,
    u16* dst, float* dstf, int dstride,
    const u16* resid, int rstride, bool relu, int rmul, int roff,
    int wave, int lane16, int quad)
{
    const int K = KT * 32;
    #pragma unroll
    for (int i = 0; i < NTW; ++i) {
        int nt = wave + 4*i, n0 = nt*16;
        float4v c[MT];
        #pragma unroll
        for (int mt = 0; mt < MT; ++mt) c[mt] = (float4v){0.f,0.f,0.f,0.f};
        #pragma unroll
        for (int ks = 0; ks < KT; ++ks) {
            short8 b = *(const short8*)(wsb + (size_t)(n0 + lane16)*K + ks*32 + quad*8);
            #pragma unroll
            for (int mt = 0; mt < MT; ++mt)
                c[mt] = __builtin_amdgcn_mfma_f32_16x16x32_bf16(A[mt][ks], b, c[mt], 0,0,0);
        }
        float bv = bias[n0 + lane16];
        #pragma unroll
        for (int mt = 0; mt < MT; ++mt)
            #pragma unroll
            for (int ii = 0; ii < 4; ++ii) {
                int dr = (mt*16 + quad*4 + ii)*rmul + roff;
                float v = c[mt][ii] + bv;
                if (resid) v += b2f(resid[dr*rstride + n0 + lane16]);
                if (relu)  v = fmaxf(v, 0.f);
                if (dst) dst [dr*dstride + n0 + lane16] = f2b(v);
                else     dstf[dr*dstride + n0 + lane16] = v;
            }
    }
}

// ---- LDS arena (u16 elements), compacted: peak live set = 25600 u16 = 50 KB ----
// stride 200 for K=192 rows, 392 for h
#define S1 200
#define SH 392
#define A_INP 0          // 16x200 inputs P     (dead after proj)
#define A_INT 3200       // 16x200 inputs T     (dead after proj)
#define A_SEQ 6400       // 32x200 seq          (dead after out-proj residual)
#define A_Q   0          // 32x200 q   (over inputs; dead after scores)
#define A_K   12800      // 32x200 k   (dead after scores)
#define A_V   19200      // 32x200 v   (dead after ctx)
#define A_CTX 0          // 32x200 ctx (over q; dead after out-proj)
#define A_X1  12800      // 32x200 x1  (over k; dead after FFN2 residual)
#define A_H   0          // 32x392 h = 12544 (over ctx+seq; dead after FFN2)
#define A_X2  19200      // 32x200 x2  (over v; dead after LN2)
#define A_Z   12800      // 16x200 z   (over x1 head)
#define A_CH  16000      // 16x200 cls hidden (over x1 tail)
#define A_FPF 0          // 16x128 f32 = 4096 u16 (over h)
#define ARENA_U16 25600

__global__ __launch_bounds__(256, 3)
void fusion_mfma_kernel(
    const float* __restrict__ perc, const float* __restrict__ tech,
    const float* __restrict__ bp,   const float* __restrict__ bt,
    const float* __restrict__ in_b, const float* __restrict__ out_b,
    const float* __restrict__ fb1,  const float* __restrict__ fb2,
    const float* __restrict__ ln1g, const float* __restrict__ ln1b,
    const float* __restrict__ ln2g, const float* __restrict__ ln2b,
    const float* __restrict__ cb1,  const float* __restrict__ cw2,
    const float* __restrict__ cb2,  const float* __restrict__ fpb,
    const u16*   __restrict__ ws,
    float* __restrict__ out, int B)
{
    __shared__ __align__(16) u16 arena[ARENA_U16];
    __shared__ float satt[16][3][2][2];   // softmax probs
    __shared__ float smu[32], srs[32], srn[16];

    const int tid = threadIdx.x;
    const int wave = tid >> 6, lane = tid & 63;
    const int lane16 = lane & 15, quad = lane >> 4;
    const int row0 = blockIdx.x * RPB;
    float* fpf = (float*)(arena + A_FPF);   // 16x128 f32 (over dead h)

    // ---- stage inputs -> bf16 LDS, float4 loads / short8 stores ----
    #pragma unroll
    for (int it = 0; it < 3; ++it) {
        int idx = it*256 + tid;           // 768 = 2 arrays * 16 rows * 24 groups-of-8
        int arr = idx >= 384 ? 1 : 0;
        int rem = arr ? idx - 384 : idx;
        int r = rem / 24, g = rem - r*24;
        const float* src = arr ? tech : perc;
        const float4* s4 = (const float4*)(src + (size_t)(row0 + r)*D + g*8);
        float4 lo = s4[0], hi = s4[1];
        short8 o;
        o[0]=(short)f2b(lo.x); o[1]=(short)f2b(lo.y); o[2]=(short)f2b(lo.z); o[3]=(short)f2b(lo.w);
        o[4]=(short)f2b(hi.x); o[5]=(short)f2b(hi.y); o[6]=(short)f2b(hi.z); o[7]=(short)f2b(hi.w);
        *(short8*)(arena + (arr ? A_INT : A_INP) + r*S1 + g*8) = o;
    }
    __syncthreads();

    // ---- proj_p / proj_t -> seq (tokens interleaved: row 2r / 2r+1) ----
    {
        short8 A1[1][6];
        load_afrags<6,1>(A1, arena + A_INP, S1, lane16, quad);
        run_gemm<6,1,3>(A1, ws + WP_OFF, bp, arena + A_SEQ, nullptr, S1,
                        nullptr, 0, false, 2, 0, wave, lane16, quad);
        load_afrags<6,1>(A1, arena + A_INT, S1, lane16, quad);
        run_gemm<6,1,3>(A1, ws + WT_OFF, bt, arena + A_SEQ, nullptr, S1,
                        nullptr, 0, false, 2, 1, wave, lane16, quad);
    }
    __syncthreads();

    // ---- qkv (A = seq, M=32); q overwrites dead input region ----
    {
        short8 A2[2][6];
        load_afrags<6,2>(A2, arena + A_SEQ, S1, lane16, quad);
        run_gemm<6,2,3>(A2, ws + INW_OFF,           in_b,       arena + A_Q, nullptr, S1,
                        nullptr, 0, false, 1, 0, wave, lane16, quad);
        run_gemm<6,2,3>(A2, ws + INW_OFF + 192*192, in_b + 192, arena + A_K, nullptr, S1,
                        nullptr, 0, false, 1, 0, wave, lane16, quad);
        run_gemm<6,2,3>(A2, ws + INW_OFF + 384*192, in_b + 384, arena + A_V, nullptr, S1,
                        nullptr, 0, false, 1, 0, wave, lane16, quad);
    }
    __syncthreads();

    // ---- attention scores + softmax fused (192 threads, b128 LDS reads) ----
    if (tid < 192) {
        int r = tid / 12, rem = tid - r*12;
        int h = rem >> 2, qt = (rem >> 1) & 1, kt = rem & 1;
        const u16* qp = arena + A_Q + (2*r + qt)*S1 + h*64;
        const u16* kp = arena + A_K + (2*r + kt)*S1 + h*64;
        float s = 0.f;
        #pragma unroll
        for (int i = 0; i < 8; ++i) {
            short8 qa = *(const short8*)(qp + i*8);
            short8 ka = *(const short8*)(kp + i*8);
            #pragma unroll
            for (int j = 0; j < 8; ++j) s += b2f((u16)qa[j]) * b2f((u16)ka[j]);
        }
        s *= 0.125f;
        float so = __shfl_xor(s, 1);      // partner kt^1, same wave (192 = 3 full waves)
        float m = fmaxf(s, so);
        float e = expf(s - m), eo = expf(so - m);
        satt[r][h][qt][kt] = e / (e + eo);
    }
    __syncthreads();

    // ---- ctx = attn @ v -> A_CTX (over dead q), short8 vectorized ----
    #pragma unroll
    for (int it = 0; it < 3; ++it) {
        int idx = it*256 + tid;          // 768 = 32 tok * 24 groups
        int tok = idx / 24, g = idx - tok*24;
        int r = tok >> 1, qt = tok & 1, h = g >> 3;
        short8 v0 = *(const short8*)(arena + A_V + (2*r    )*S1 + g*8);
        short8 v1 = *(const short8*)(arena + A_V + (2*r + 1)*S1 + g*8);
        float p0 = satt[r][h][qt][0], p1 = satt[r][h][qt][1];
        short8 o;
        #pragma unroll
        for (int j = 0; j < 8; ++j)
            o[j] = (short)f2b(p0*b2f((u16)v0[j]) + p1*b2f((u16)v1[j]));
        *(short8*)(arena + A_CTX + tok*S1 + g*8) = o;
    }
    __syncthreads();

    // ---- out-proj + residual(seq) -> x1 (pre-LN1, over dead k) ----
    {
        short8 A2[2][6];
        load_afrags<6,2>(A2, arena + A_CTX, S1, lane16, quad);
        run_gemm<6,2,3>(A2, ws + OUTW_OFF, out_b, arena + A_X1, nullptr, S1,
                        arena + A_SEQ, S1, false, 1, 0, wave, lane16, quad);
    }
    __syncthreads();

    // ---- LN1 stats: short8 loads + 8-lane shuffle reduce (no LDS staging) ----
    {
        int tok = tid >> 3, sub = tid & 7;
        const u16* p = arena + A_X1 + tok*S1 + sub*24;
        float s = 0.f, s2 = 0.f;
        #pragma unroll
        for (int i = 0; i < 3; ++i) {
            short8 v = *(const short8*)(p + i*8);
            #pragma unroll
            for (int j = 0; j < 8; ++j) { float y = b2f((u16)v[j]); s += y; s2 += y*y; }
        }
        s  += __shfl_xor(s, 1);  s  += __shfl_xor(s, 2);  s  += __shfl_xor(s, 4);
        s2 += __shfl_xor(s2, 1); s2 += __shfl_xor(s2, 2); s2 += __shfl_xor(s2, 4);
        if (sub == 0) {
            float mu = s * (1.f/192.f);
            float var = s2 * (1.f/192.f) - mu*mu;
            smu[tok] = mu; srs[tok] = rsqrtf(var + 1e-5f);
        }
    }
    __syncthreads();
    // ---- LN1 apply (in-place, short8) ----
    #pragma unroll
    for (int it = 0; it < 3; ++it) {
        int idx = it*256 + tid;          // 768
        int tok = idx / 24, g = idx - tok*24;
        float mu = smu[tok], rs = srs[tok];
        float4 ga = ((const float4*)(ln1g + g*8))[0], gb = ((const float4*)(ln1g + g*8))[1];
        float4 ba = ((const float4*)(ln1b + g*8))[0], bb = ((const float4*)(ln1b + g*8))[1];
        float gg[8]  = {ga.x,ga.y,ga.z,ga.w,gb.x,gb.y,gb.z,gb.w};
        float bbv[8] = {ba.x,ba.y,ba.z,ba.w,bb.x,bb.y,bb.z,bb.w};
        u16* p = arena + A_X1 + tok*S1 + g*8;
        short8 v = *(const short8*)p;
        short8 o;
        #pragma unroll
        for (int j = 0; j < 8; ++j)
            o[j] = (short)f2b((b2f((u16)v[j]) - mu)*rs*gg[j] + bbv[j]);
        *(short8*)p = o;
    }
    __syncthreads();

    // ---- FFN1 (relu) -> h (over dead ctx+seq) ----
    {
        short8 A2[2][6];
        load_afrags<6,2>(A2, arena + A_X1, S1, lane16, quad);
        run_gemm<6,2,6>(A2, ws + FW1_OFF, fb1, arena + A_H, nullptr, SH,
                        nullptr, 0, true, 1, 0, wave, lane16, quad);
    }
    __syncthreads();

    // ---- FFN2 (K=384, chunked) + residual(x1) -> x2 (over dead v) ----
    {
        float4v c[3][2];
        #pragma unroll
        for (int i = 0; i < 3; ++i) { c[i][0] = (float4v){0,0,0,0}; c[i][1] = (float4v){0,0,0,0}; }
        #pragma unroll
        for (int kc = 0; kc < 2; ++kc) {
            short8 Af[2][6];
            load_afrags<6,2>(Af, arena + A_H + kc*192, SH, lane16, quad);
            #pragma unroll
            for (int i = 0; i < 3; ++i) {
                int n0 = (wave + 4*i)*16;
                #pragma unroll
                for (int ks = 0; ks < 6; ++ks) {
                    short8 b = *(const short8*)(ws + FW2_OFF + (size_t)(n0+lane16)*384 + kc*192 + ks*32 + quad*8);
                    c[i][0] = __builtin_amdgcn_mfma_f32_16x16x32_bf16(Af[0][ks], b, c[i][0], 0,0,0);
                    c[i][1] = __builtin_amdgcn_mfma_f32_16x16x32_bf16(Af[1][ks], b, c[i][1], 0,0,0);
                }
            }
        }
        #pragma unroll
        for (int i = 0; i < 3; ++i) {
            int n0 = (wave + 4*i)*16;
            float bv = fb2[n0 + lane16];
            #pragma unroll
            for (int mt = 0; mt < 2; ++mt)
                #pragma unroll
                for (int ii = 0; ii < 4; ++ii) {
                    int dr = mt*16 + quad*4 + ii;
                    float v = c[i][mt][ii] + bv + b2f(arena[A_X1 + dr*S1 + n0 + lane16]);
                    arena[A_X2 + dr*S1 + n0 + lane16] = f2b(v);
                }
        }
    }
    __syncthreads();

    // ---- LN2 stats ----
    {
        int tok = tid >> 3, sub = tid & 7;
        const u16* p = arena + A_X2 + tok*S1 + sub*24;
        float s = 0.f, s2 = 0.f;
        #pragma unroll
        for (int i = 0; i < 3; ++i) {
            short8 v = *(const short8*)(p + i*8);
            #pragma unroll
            for (int j = 0; j < 8; ++j) { float y = b2f((u16)v[j]); s += y; s2 += y*y; }
        }
        s  += __shfl_xor(s, 1);  s  += __shfl_xor(s, 2);  s  += __shfl_xor(s, 4);
        s2 += __shfl_xor(s2, 1); s2 += __shfl_xor(s2, 2); s2 += __shfl_xor(s2, 4);
        if (sub == 0) {
            float mu = s * (1.f/192.f);
            float var = s2 * (1.f/192.f) - mu*mu;
            smu[tok] = mu; srs[tok] = rsqrtf(var + 1e-5f);
        }
    }
    __syncthreads();
    // ---- LN2 apply + token-mean -> z (over dead x1 head) ----
    #pragma unroll
    for (int it = 0; it < 2; ++it) {
        int idx = it*256 + tid;          // 384 = 16 r * 24 groups
        if (idx < 384) {
            int r = idx / 24, g = idx - r*24;
            float mu0 = smu[2*r], rs0 = srs[2*r];
            float mu1 = smu[2*r+1], rs1 = srs[2*r+1];
            float4 ga = ((const float4*)(ln2g + g*8))[0], gb = ((const float4*)(ln2g + g*8))[1];
            float4 ba = ((const float4*)(ln2b + g*8))[0], bb = ((const float4*)(ln2b + g*8))[1];
            float gg[8]  = {ga.x,ga.y,ga.z,ga.w,gb.x,gb.y,gb.z,gb.w};
            float bbv[8] = {ba.x,ba.y,ba.z,ba.w,bb.x,bb.y,bb.z,bb.w};
            short8 x0 = *(const short8*)(arena + A_X2 + (2*r    )*S1 + g*8);
            short8 x1 = *(const short8*)(arena + A_X2 + (2*r + 1)*S1 + g*8);
            short8 o;
            #pragma unroll
            for (int j = 0; j < 8; ++j) {
                float n0 = (b2f((u16)x0[j]) - mu0)*rs0*gg[j] + bbv[j];
                float n1 = (b2f((u16)x1[j]) - mu1)*rs1*gg[j] + bbv[j];
                o[j] = (short)f2b(0.5f*(n0 + n1));
            }
            *(short8*)(arena + A_Z + r*S1 + g*8) = o;
        }
    }
    __syncthreads();

    // ---- heads: cls1 (relu -> ch), fingerprint (f32 -> fpf over dead h) ----
    {
        short8 A1[1][6];
        load_afrags<6,1>(A1, arena + A_Z, S1, lane16, quad);
        run_gemm<6,1,3>(A1, ws + CW1_OFF, cb1, arena + A_CH, nullptr, S1,
                        nullptr, 0, true, 1, 0, wave, lane16, quad);
        run_gemm<6,1,2>(A1, ws + FPW_OFF, fpb, nullptr, fpf, 128,
                        nullptr, 0, false, 1, 0, wave, lane16, quad);
    }
    __syncthreads();

    // ---- cls2+sigmoid (waves 0-2, split-K x4 + shuffle) || fp-norm partials (wave 3) ----
    if (tid < 192) {
        int g4 = tid >> 2, sub = tid & 3;
        int r = g4 / 3, cc = g4 - r*3;
        const float* w = cw2 + (size_t)cc * D + sub*48;
        const u16* hr = arena + A_CH + r*S1 + sub*48;
        float a = 0.f;
        #pragma unroll
        for (int i = 0; i < 6; ++i) {
            short8 hv = *(const short8*)(hr + i*8);
            float4 w0 = ((const float4*)w)[2*i], w1 = ((const float4*)w)[2*i+1];
            float wv[8] = {w0.x,w0.y,w0.z,w0.w,w1.x,w1.y,w1.z,w1.w};
            #pragma unroll
            for (int j = 0; j < 8; ++j) a += wv[j] * b2f((u16)hv[j]);
        }
        a += __shfl_xor(a, 1); a += __shfl_xor(a, 2);
        if (sub == 0) {
            a += cb2[cc];
            out[(size_t)cc * B + (size_t)(row0 + r)] = 1.f / (1.f + expf(-a));
        }
    } else {
        int t = tid - 192;               // 64 threads: 16 rows x 4-lane split
        int r = t >> 2, sub = t & 3;
        const float4* fp4 = (const float4*)(fpf + r*128 + sub*32);
        float s2 = 0.f;
        #pragma unroll
        for (int i = 0; i < 8; ++i) {
            float4 v = fp4[i];
            s2 += v.x*v.x + v.y*v.y + v.z*v.z + v.w*v.w;
        }
        s2 += __shfl_xor(s2, 1); s2 += __shfl_xor(s2, 2);
        if (sub == 0) srn[r] = 1.f / fmaxf(sqrtf(s2), 1e-12f);
    }
    __syncthreads();

    // ---- fingerprint writeout (float4) ----
    #pragma unroll
    for (int it = 0; it < 2; ++it) {
        int idx = it*256 + tid;          // 512 = 16 r * 32 float4
        int r = idx >> 5, c = idx & 31;
        float4 v = ((const float4*)(fpf + r*128))[c];
        float sc = srn[r];
        float4 o; o.x = v.x*sc; o.y = v.y*sc; o.z = v.z*sc; o.w = v.w*sc;
        ((float4*)(out + (size_t)3*B + (size_t)(row0 + r)*128))[c] = o;
    }
}

extern "C" void kernel_launch(void* const* d_in, const int* in_sizes, int n_in,
                              void* d_out, int out_size, void* d_ws, size_t ws_size,
                              hipStream_t stream) {
    if (ws_size < (size_t)W_TOTAL * 2) return;   // visible failure -> ws too small

    const float* perc = (const float*)d_in[0];
    const float* tech = (const float*)d_in[1];
    const float* Wp   = (const float*)d_in[2];
    const float* bp   = (const float*)d_in[3];
    const float* Wt   = (const float*)d_in[4];
    const float* bt   = (const float*)d_in[5];
    const float* in_w = (const float*)d_in[6];
    const float* in_b = (const float*)d_in[7];
    const float* ow   = (const float*)d_in[8];
    const float* ob   = (const float*)d_in[9];
    const float* fw1  = (const float*)d_in[10];
    const float* fb1  = (const float*)d_in[11];
    const float* fw2  = (const float*)d_in[12];
    const float* fb2  = (const float*)d_in[13];
    const float* ln1g = (const float*)d_in[14];
    const float* ln1b = (const float*)d_in[15];
    const float* ln2g = (const float*)d_in[16];
    const float* ln2b = (const float*)d_in[17];
    const float* cw1  = (const float*)d_in[18];
    const float* cb1  = (const float*)d_in[19];
    const float* cw2  = (const float*)d_in[20];
    const float* cb2  = (const float*)d_in[21];
    const float* fpw  = (const float*)d_in[22];
    const float* fpb  = (const float*)d_in[23];

    u16* ws = (u16*)d_ws;
    int B = in_sizes[0] / D;

    hipLaunchKernelGGL(cvt_weights, dim3((W_TOTAL + 255)/256), dim3(256), 0, stream,
                       Wp, Wt, in_w, ow, fw1, fw2, cw1, fpw, ws);

    hipLaunchKernelGGL(fusion_mfma_kernel, dim3(B / RPB), dim3(256), 0, stream,
                       perc, tech, bp, bt, in_b, ob, fb1, fb2,
                       ln1g, ln1b, ln2g, ln2b, cb1, cw2, cb2, fpb,
                       ws, (float*)d_out, B);
}

// Round 2
// 387.097 us; speedup vs baseline: 1.6222x; 1.5069x over previous
//
#include <hip/hip_runtime.h>
#include <hip/hip_bf16.h>
#include <math.h>

#define D 192
#define RPB 16                       // rows per block -> M = 32 tokens
typedef unsigned short u16;
typedef __attribute__((ext_vector_type(8))) short short8;   // 8 bf16 (4 VGPRs)
typedef __attribute__((ext_vector_type(4))) float float4v;  // MFMA C/D

__device__ __forceinline__ float b2f(u16 u){ union{unsigned i; float f;}c; c.i=(unsigned)u<<16; return c.f; }
__device__ __forceinline__ u16  f2b(float f){
    union{float f; unsigned i;}c; c.f=f;
    unsigned r = c.i + 0x7FFFu + ((c.i>>16)&1u);   // RTNE
    return (u16)(r>>16);
}

// ---- bf16 weight arena in d_ws: 16x32 wave-tiles, element offsets ----
// swz(n,k) = ((n>>4)*(K>>5) + (k>>5))*512 + (n&15)*32 + (k&31)
// (row-block offsets at multiples of 16 rows coincide with row-major offsets)
#define WP_OFF   0
#define WT_OFF   36864
#define INW_OFF  73728
#define OUTW_OFF 184320
#define FW1_OFF  221184
#define FW2_OFF  294912
#define CW1_OFF  368640
#define FPW_OFF  405504
#define W_TOTAL  430080            // elements; 860160 bytes

__global__ __launch_bounds__(256)
void cvt_weights(const float* __restrict__ Wp, const float* __restrict__ Wt,
                 const float* __restrict__ in_w, const float* __restrict__ out_w,
                 const float* __restrict__ fw1, const float* __restrict__ fw2,
                 const float* __restrict__ cw1, const float* __restrict__ fpw,
                 u16* __restrict__ ws)
{
    int idx = blockIdx.x * 256 + threadIdx.x;
    if (idx >= W_TOTAL) return;
    const float* src; int off; int K = 192;
    if      (idx < WT_OFF)   { src = Wp;   off = WP_OFF; }
    else if (idx < INW_OFF)  { src = Wt;   off = WT_OFF; }
    else if (idx < OUTW_OFF) { src = in_w; off = INW_OFF; }
    else if (idx < FW1_OFF)  { src = out_w;off = OUTW_OFF; }
    else if (idx < FW2_OFF)  { src = fw1;  off = FW1_OFF; }
    else if (idx < CW1_OFF)  { src = fw2;  off = FW2_OFF; K = 384; }
    else if (idx < FPW_OFF)  { src = cw1;  off = CW1_OFF; }
    else                     { src = fpw;  off = FPW_OFF; }
    int lin = idx - off;
    int n = lin / K, k = lin - n*K;
    int swz = ((n>>4)*(K>>5) + (k>>5))*512 + ((n&15)<<5) + (k&31);
    ws[off + swz] = f2b(src[lin]);
}

// A-frag: lane holds A[m = mt*16 + lane16][k = quad*8 + j] for k-step ks (k += 32*ks)
template<int KT, int MT>
__device__ __forceinline__ void load_afrags(short8 (&A)[MT][KT], const u16* base,
                                            int stride, int lane16, int quad)
{
    #pragma unroll
    for (int mt = 0; mt < MT; ++mt)
        #pragma unroll
        for (int ks = 0; ks < KT; ++ks)
            A[mt][ks] = *(const short8*)(base + (mt*16 + lane16)*stride + ks*32 + quad*8);
}

// C tile (M=MT*16, N=NTW*4 waves*16): B streamed from swizzled global bf16 tiles.
// C/D layout: row = quad*4 + reg, col = lane16 (m89-verified).
template<int KT, int MT, int NTW>
__device__ __forceinline__ void run_gemm(const short8 (&A)[MT][KT],
    const u16* __restrict__ wsb, const float* __restrict__ bias,
    u16* dst, float* dstf, int dstride,
    const u16* resid, int rstride, bool relu, int rmul, int roff,
    int wave, int lane16, int quad)
{
    #pragma unroll
    for (int i = 0; i < NTW; ++i) {
        int nt = wave + 4*i, n0 = nt*16;
        float4v c[MT];
        #pragma unroll
        for (int mt = 0; mt < MT; ++mt) c[mt] = (float4v){0.f,0.f,0.f,0.f};
        #pragma unroll
        for (int ks = 0; ks < KT; ++ks) {
            short8 b = *(const short8*)(wsb + (size_t)((nt*KT + ks)<<9) + (lane16<<5) + (quad<<3));
            #pragma unroll
            for (int mt = 0; mt < MT; ++mt)
                c[mt] = __builtin_amdgcn_mfma_f32_16x16x32_bf16(A[mt][ks], b, c[mt], 0,0,0);
        }
        float bv = bias[n0 + lane16];
        #pragma unroll
        for (int mt = 0; mt < MT; ++mt)
            #pragma unroll
            for (int ii = 0; ii < 4; ++ii) {
                int dr = (mt*16 + quad*4 + ii)*rmul + roff;
                float v = c[mt][ii] + bv;
                if (resid) v += b2f(resid[dr*rstride + n0 + lane16]);
                if (relu)  v = fmaxf(v, 0.f);
                if (dst) dst [dr*dstride + n0 + lane16] = f2b(v);
                else     dstf[dr*dstride + n0 + lane16] = v;
            }
    }
}

// ---- LDS arena (u16 elements), peak live set = 19200 u16 = 37.5 KB ----
// stride 200 for K=192 rows, 392 for h
#define S1 200
#define SH 392
#define A_INP 0          // 16x200 inputs P     (dead after proj)
#define A_INT 3200       // 16x200 inputs T     (dead after proj)
#define A_SEQ 6400       // 32x200 seq          (dead after out-proj residual)
#define A_Q   0          // 32x200 q   (over inputs; dead after scores)
#define A_K   12800      // 32x200 k   (dead after scores)
#define A_CTX 0          // 32x200 ctx (over q; dead after out-proj)
#define A_X1  12800      // 32x200 x1  (over k; FFN2 residual written IN-PLACE)
#define A_H   0          // 32x392 = 12544 (over ctx+seq; dead after FFN2)
#define A_Z   0          // 16x200 z   (over h head, h dead)
#define A_CH  3200       // 16x200 cls hidden
#define A_FPF 6400       // 16x128 f32 = 4096 u16 (over h mid)
#define ARENA_U16 19200

__global__ __launch_bounds__(256, 4)
void fusion_mfma_kernel(
    const float* __restrict__ perc, const float* __restrict__ tech,
    const float* __restrict__ bp,   const float* __restrict__ bt,
    const float* __restrict__ in_b, const float* __restrict__ out_b,
    const float* __restrict__ fb1,  const float* __restrict__ fb2,
    const float* __restrict__ ln1g, const float* __restrict__ ln1b,
    const float* __restrict__ ln2g, const float* __restrict__ ln2b,
    const float* __restrict__ cb1,  const float* __restrict__ cw2,
    const float* __restrict__ cb2,  const float* __restrict__ fpb,
    const u16*   __restrict__ ws,
    float* __restrict__ out, int B)
{
    __shared__ __align__(16) u16 arena[ARENA_U16];
    __shared__ float satt[16][3][4];      // softmax probs [qt*2+kt]
    __shared__ float smu[32], srs[32], srn[16];

    const int tid = threadIdx.x;
    const int wave = tid >> 6, lane = tid & 63;
    const int lane16 = lane & 15, quad = lane >> 4;
    const int row0 = blockIdx.x * RPB;
    float* fpf = (float*)(arena + A_FPF);   // 16x128 f32 (over dead h)

    // ---- stage inputs -> bf16 LDS, float4 loads / short8 stores ----
    #pragma unroll
    for (int it = 0; it < 3; ++it) {
        int idx = it*256 + tid;           // 768 = 2 arrays * 16 rows * 24 groups-of-8
        int arr = idx >= 384 ? 1 : 0;
        int rem = arr ? idx - 384 : idx;
        int r = rem / 24, g = rem - r*24;
        const float* src = arr ? tech : perc;
        const float4* s4 = (const float4*)(src + (size_t)(row0 + r)*D + g*8);
        float4 lo = s4[0], hi = s4[1];
        short8 o;
        o[0]=(short)f2b(lo.x); o[1]=(short)f2b(lo.y); o[2]=(short)f2b(lo.z); o[3]=(short)f2b(lo.w);
        o[4]=(short)f2b(hi.x); o[5]=(short)f2b(hi.y); o[6]=(short)f2b(hi.z); o[7]=(short)f2b(hi.w);
        *(short8*)(arena + (arr ? A_INT : A_INP) + r*S1 + g*8) = o;
    }
    __syncthreads();

    // ---- proj_p / proj_t -> seq (tokens interleaved: row 2r / 2r+1) ----
    {
        short8 A1[1][6];
        load_afrags<6,1>(A1, arena + A_INP, S1, lane16, quad);
        run_gemm<6,1,3>(A1, ws + WP_OFF, bp, arena + A_SEQ, nullptr, S1,
                        nullptr, 0, false, 2, 0, wave, lane16, quad);
        load_afrags<6,1>(A1, arena + A_INT, S1, lane16, quad);
        run_gemm<6,1,3>(A1, ws + WT_OFF, bt, arena + A_SEQ, nullptr, S1,
                        nullptr, 0, false, 2, 1, wave, lane16, quad);
    }
    __syncthreads();

    // ---- qkv: q,k -> LDS; V kept in registers (C-layout holds token pairs in-lane) ----
    float4v vreg[3][2];
    {
        short8 A2[2][6];
        load_afrags<6,2>(A2, arena + A_SEQ, S1, lane16, quad);
        run_gemm<6,2,3>(A2, ws + INW_OFF,           in_b,       arena + A_Q, nullptr, S1,
                        nullptr, 0, false, 1, 0, wave, lane16, quad);
        run_gemm<6,2,3>(A2, ws + INW_OFF + 192*192, in_b + 192, arena + A_K, nullptr, S1,
                        nullptr, 0, false, 1, 0, wave, lane16, quad);
        #pragma unroll
        for (int i = 0; i < 3; ++i) {
            int nt = wave + 4*i;
            vreg[i][0] = (float4v){0.f,0.f,0.f,0.f};
            vreg[i][1] = (float4v){0.f,0.f,0.f,0.f};
            #pragma unroll
            for (int ks = 0; ks < 6; ++ks) {
                short8 b = *(const short8*)(ws + INW_OFF + 384*192 + ((nt*6 + ks)<<9) + (lane16<<5) + (quad<<3));
                vreg[i][0] = __builtin_amdgcn_mfma_f32_16x16x32_bf16(A2[0][ks], b, vreg[i][0], 0,0,0);
                vreg[i][1] = __builtin_amdgcn_mfma_f32_16x16x32_bf16(A2[1][ks], b, vreg[i][1], 0,0,0);
            }
            float bv = in_b[384 + nt*16 + lane16];
            #pragma unroll
            for (int mt = 0; mt < 2; ++mt)
                #pragma unroll
                for (int ii = 0; ii < 4; ++ii) vreg[i][mt][ii] += bv;
        }
    }
    __syncthreads();

    // ---- attention scores + softmax fused (192 threads, b128 LDS reads) ----
    if (tid < 192) {
        int r = tid / 12, rem = tid - r*12;
        int h = rem >> 2, qt = (rem >> 1) & 1, kt = rem & 1;
        const u16* qp = arena + A_Q + (2*r + qt)*S1 + h*64;
        const u16* kp = arena + A_K + (2*r + kt)*S1 + h*64;
        float s = 0.f;
        #pragma unroll
        for (int i = 0; i < 8; ++i) {
            short8 qa = *(const short8*)(qp + i*8);
            short8 ka = *(const short8*)(kp + i*8);
            #pragma unroll
            for (int j = 0; j < 8; ++j) s += b2f((u16)qa[j]) * b2f((u16)ka[j]);
        }
        s *= 0.125f;
        float so = __shfl_xor(s, 1);      // partner kt^1, same wave
        float m = fmaxf(s, so);
        float e = expf(s - m), eo = expf(so - m);
        satt[r][h][qt*2 + kt] = e / (e + eo);
    }
    __syncthreads();

    // ---- ctx = attn @ v, fully in-register (writes over dead q) ----
    #pragma unroll
    for (int i = 0; i < 3; ++i) {
        int col = (wave + 4*i)*16 + lane16;
        int h = col >> 6;
        #pragma unroll
        for (int mt = 0; mt < 2; ++mt)
            #pragma unroll
            for (int p = 0; p < 2; ++p) {
                int R = mt*16 + quad*4 + 2*p;      // even token row
                int r = R >> 1;
                float4 pa = *(const float4*)&satt[r][h][0];  // p00,p01,p10,p11
                float v0 = vreg[i][mt][2*p], v1 = vreg[i][mt][2*p+1];
                arena[A_CTX + R*S1 + col]       = f2b(pa.x*v0 + pa.y*v1);
                arena[A_CTX + (R+1)*S1 + col]   = f2b(pa.z*v0 + pa.w*v1);
            }
    }
    __syncthreads();

    // ---- out-proj + residual(seq) -> x1 (pre-LN1, over dead k) ----
    {
        short8 A2[2][6];
        load_afrags<6,2>(A2, arena + A_CTX, S1, lane16, quad);
        run_gemm<6,2,3>(A2, ws + OUTW_OFF, out_b, arena + A_X1, nullptr, S1,
                        arena + A_SEQ, S1, false, 1, 0, wave, lane16, quad);
    }
    __syncthreads();

    // ---- LN1 stats: short8 loads + 8-lane shuffle reduce ----
    {
        int tok = tid >> 3, sub = tid & 7;
        const u16* p = arena + A_X1 + tok*S1 + sub*24;
        float s = 0.f, s2 = 0.f;
        #pragma unroll
        for (int i = 0; i < 3; ++i) {
            short8 v = *(const short8*)(p + i*8);
            #pragma unroll
            for (int j = 0; j < 8; ++j) { float y = b2f((u16)v[j]); s += y; s2 += y*y; }
        }
        s  += __shfl_xor(s, 1);  s  += __shfl_xor(s, 2);  s  += __shfl_xor(s, 4);
        s2 += __shfl_xor(s2, 1); s2 += __shfl_xor(s2, 2); s2 += __shfl_xor(s2, 4);
        if (sub == 0) {
            float mu = s * (1.f/192.f);
            float var = s2 * (1.f/192.f) - mu*mu;
            smu[tok] = mu; srs[tok] = rsqrtf(var + 1e-5f);
        }
    }
    __syncthreads();
    // ---- LN1 apply (in-place, short8) ----
    #pragma unroll
    for (int it = 0; it < 3; ++it) {
        int idx = it*256 + tid;          // 768
        int tok = idx / 24, g = idx - tok*24;
        float mu = smu[tok], rs = srs[tok];
        float4 ga = ((const float4*)(ln1g + g*8))[0], gb = ((const float4*)(ln1g + g*8))[1];
        float4 ba = ((const float4*)(ln1b + g*8))[0], bb = ((const float4*)(ln1b + g*8))[1];
        float gg[8]  = {ga.x,ga.y,ga.z,ga.w,gb.x,gb.y,gb.z,gb.w};
        float bbv[8] = {ba.x,ba.y,ba.z,ba.w,bb.x,bb.y,bb.z,bb.w};
        u16* p = arena + A_X1 + tok*S1 + g*8;
        short8 v = *(const short8*)p;
        short8 o;
        #pragma unroll
        for (int j = 0; j < 8; ++j)
            o[j] = (short)f2b((b2f((u16)v[j]) - mu)*rs*gg[j] + bbv[j]);
        *(short8*)p = o;
    }
    __syncthreads();

    // ---- FFN1 (relu) -> h (over dead ctx+seq) ----
    {
        short8 A2[2][6];
        load_afrags<6,2>(A2, arena + A_X1, S1, lane16, quad);
        run_gemm<6,2,6>(A2, ws + FW1_OFF, fb1, arena + A_H, nullptr, SH,
                        nullptr, 0, true, 1, 0, wave, lane16, quad);
    }
    __syncthreads();

    // ---- FFN2 (K=384) + residual, written IN-PLACE over x1 -> pre-LN2 ----
    {
        float4v c[3][2];
        #pragma unroll
        for (int i = 0; i < 3; ++i) { c[i][0] = (float4v){0,0,0,0}; c[i][1] = (float4v){0,0,0,0}; }
        #pragma unroll
        for (int kc = 0; kc < 2; ++kc) {
            short8 Af[2][6];
            load_afrags<6,2>(Af, arena + A_H + kc*192, SH, lane16, quad);
            #pragma unroll
            for (int i = 0; i < 3; ++i) {
                int nt = wave + 4*i;
                #pragma unroll
                for (int ks = 0; ks < 6; ++ks) {
                    short8 b = *(const short8*)(ws + FW2_OFF + ((nt*12 + kc*6 + ks)<<9) + (lane16<<5) + (quad<<3));
                    c[i][0] = __builtin_amdgcn_mfma_f32_16x16x32_bf16(Af[0][ks], b, c[i][0], 0,0,0);
                    c[i][1] = __builtin_amdgcn_mfma_f32_16x16x32_bf16(Af[1][ks], b, c[i][1], 0,0,0);
                }
            }
        }
        #pragma unroll
        for (int i = 0; i < 3; ++i) {
            int n0 = (wave + 4*i)*16;
            float bv = fb2[n0 + lane16];
            #pragma unroll
            for (int mt = 0; mt < 2; ++mt)
                #pragma unroll
                for (int ii = 0; ii < 4; ++ii) {
                    int dr = mt*16 + quad*4 + ii;
                    u16* p = arena + A_X1 + dr*S1 + n0 + lane16;
                    *p = f2b(c[i][mt][ii] + bv + b2f(*p));   // same-thread RMW, safe
                }
        }
    }
    __syncthreads();

    // ---- LN2 stats ----
    {
        int tok = tid >> 3, sub = tid & 7;
        const u16* p = arena + A_X1 + tok*S1 + sub*24;
        float s = 0.f, s2 = 0.f;
        #pragma unroll
        for (int i = 0; i < 3; ++i) {
            short8 v = *(const short8*)(p + i*8);
            #pragma unroll
            for (int j = 0; j < 8; ++j) { float y = b2f((u16)v[j]); s += y; s2 += y*y; }
        }
        s  += __shfl_xor(s, 1);  s  += __shfl_xor(s, 2);  s  += __shfl_xor(s, 4);
        s2 += __shfl_xor(s2, 1); s2 += __shfl_xor(s2, 2); s2 += __shfl_xor(s2, 4);
        if (sub == 0) {
            float mu = s * (1.f/192.f);
            float var = s2 * (1.f/192.f) - mu*mu;
            smu[tok] = mu; srs[tok] = rsqrtf(var + 1e-5f);
        }
    }
    __syncthreads();
    // ---- LN2 apply + token-mean -> z (over dead h head) ----
    #pragma unroll
    for (int it = 0; it < 2; ++it) {
        int idx = it*256 + tid;          // 384 = 16 r * 24 groups
        if (idx < 384) {
            int r = idx / 24, g = idx - r*24;
            float mu0 = smu[2*r], rs0 = srs[2*r];
            float mu1 = smu[2*r+1], rs1 = srs[2*r+1];
            float4 ga = ((const float4*)(ln2g + g*8))[0], gb = ((const float4*)(ln2g + g*8))[1];
            float4 ba = ((const float4*)(ln2b + g*8))[0], bb = ((const float4*)(ln2b + g*8))[1];
            float gg[8]  = {ga.x,ga.y,ga.z,ga.w,gb.x,gb.y,gb.z,gb.w};
            float bbv[8] = {ba.x,ba.y,ba.z,ba.w,bb.x,bb.y,bb.z,bb.w};
            short8 x0 = *(const short8*)(arena + A_X1 + (2*r    )*S1 + g*8);
            short8 x1 = *(const short8*)(arena + A_X1 + (2*r + 1)*S1 + g*8);
            short8 o;
            #pragma unroll
            for (int j = 0; j < 8; ++j) {
                float n0 = (b2f((u16)x0[j]) - mu0)*rs0*gg[j] + bbv[j];
                float n1 = (b2f((u16)x1[j]) - mu1)*rs1*gg[j] + bbv[j];
                o[j] = (short)f2b(0.5f*(n0 + n1));
            }
            *(short8*)(arena + A_Z + r*S1 + g*8) = o;
        }
    }
    __syncthreads();

    // ---- heads: cls1 (relu -> ch), fingerprint (f32 -> fpf over dead h) ----
    {
        short8 A1[1][6];
        load_afrags<6,1>(A1, arena + A_Z, S1, lane16, quad);
        run_gemm<6,1,3>(A1, ws + CW1_OFF, cb1, arena + A_CH, nullptr, S1,
                        nullptr, 0, true, 1, 0, wave, lane16, quad);
        run_gemm<6,1,2>(A1, ws + FPW_OFF, fpb, nullptr, fpf, 128,
                        nullptr, 0, false, 1, 0, wave, lane16, quad);
    }
    __syncthreads();

    // ---- cls2+sigmoid (waves 0-2, split-K x4 + shuffle) || fp-norm partials (wave 3) ----
    if (tid < 192) {
        int g4 = tid >> 2, sub = tid & 3;
        int r = g4 / 3, cc = g4 - r*3;
        const float* w = cw2 + (size_t)cc * D + sub*48;
        const u16* hr = arena + A_CH + r*S1 + sub*48;
        float a = 0.f;
        #pragma unroll
        for (int i = 0; i < 6; ++i) {
            short8 hv = *(const short8*)(hr + i*8);
            float4 w0 = ((const float4*)w)[2*i], w1 = ((const float4*)w)[2*i+1];
            float wv[8] = {w0.x,w0.y,w0.z,w0.w,w1.x,w1.y,w1.z,w1.w};
            #pragma unroll
            for (int j = 0; j < 8; ++j) a += wv[j] * b2f((u16)hv[j]);
        }
        a += __shfl_xor(a, 1); a += __shfl_xor(a, 2);
        if (sub == 0) {
            a += cb2[cc];
            out[(size_t)cc * B + (size_t)(row0 + r)] = 1.f / (1.f + expf(-a));
        }
    } else {
        int t = tid - 192;               // 64 threads: 16 rows x 4-lane split
        int r = t >> 2, sub = t & 3;
        const float4* fp4 = (const float4*)(fpf + r*128 + sub*32);
        float s2 = 0.f;
        #pragma unroll
        for (int i = 0; i < 8; ++i) {
            float4 v = fp4[i];
            s2 += v.x*v.x + v.y*v.y + v.z*v.z + v.w*v.w;
        }
        s2 += __shfl_xor(s2, 1); s2 += __shfl_xor(s2, 2);
        if (sub == 0) srn[r] = 1.f / fmaxf(sqrtf(s2), 1e-12f);
    }
    __syncthreads();

    // ---- fingerprint writeout (float4) ----
    #pragma unroll
    for (int it = 0; it < 2; ++it) {
        int idx = it*256 + tid;          // 512 = 16 r * 32 float4
        int r = idx >> 5, c = idx & 31;
        float4 v = ((const float4*)(fpf + r*128))[c];
        float sc = srn[r];
        float4 o; o.x = v.x*sc; o.y = v.y*sc; o.z = v.z*sc; o.w = v.w*sc;
        ((float4*)(out + (size_t)3*B + (size_t)(row0 + r)*128))[c] = o;
    }
}

extern "C" void kernel_launch(void* const* d_in, const int* in_sizes, int n_in,
                              void* d_out, int out_size, void* d_ws, size_t ws_size,
                              hipStream_t stream) {
    if (ws_size < (size_t)W_TOTAL * 2) return;   // visible failure -> ws too small

    const float* perc = (const float*)d_in[0];
    const float* tech = (const float*)d_in[1];
    const float* Wp   = (const float*)d_in[2];
    const float* bp   = (const float*)d_in[3];
    const float* Wt   = (const float*)d_in[4];
    const float* bt   = (const float*)d_in[5];
    const float* in_w = (const float*)d_in[6];
    const float* in_b = (const float*)d_in[7];
    const float* ow   = (const float*)d_in[8];
    const float* ob   = (const float*)d_in[9];
    const float* fw1  = (const float*)d_in[10];
    const float* fb1  = (const float*)d_in[11];
    const float* fw2  = (const float*)d_in[12];
    const float* fb2  = (const float*)d_in[13];
    const float* ln1g = (const float*)d_in[14];
    const float* ln1b = (const float*)d_in[15];
    const float* ln2g = (const float*)d_in[16];
    const float* ln2b = (const float*)d_in[17];
    const float* cw1  = (const float*)d_in[18];
    const float* cb1  = (const float*)d_in[19];
    const float* cw2  = (const float*)d_in[20];
    const float* cb2  = (const float*)d_in[21];
    const float* fpw  = (const float*)d_in[22];
    const float* fpb  = (const float*)d_in[23];

    u16* ws = (u16*)d_ws;
    int B = in_sizes[0] / D;

    hipLaunchKernelGGL(cvt_weights, dim3((W_TOTAL + 255)/256), dim3(256), 0, stream,
                       Wp, Wt, in_w, ow, fw1, fw2, cw1, fpw, ws);

    hipLaunchKernelGGL(fusion_mfma_kernel, dim3(B / RPB), dim3(256), 0, stream,
                       perc, tech, bp, bt, in_b, ob, fb1, fb2,
                       ln1g, ln1b, ln2g, ln2b, cb1, cw2, cb2, fpb,
                       ws, (float*)d_out, B);
}